// Round 9
// baseline (139.466 us; speedup 1.0000x reference)
//
#include <hip/hip_runtime.h>
#include <hip/hip_bf16.h>

#define SEQ 14
#define IN 24
#define H 64
#define CLS 10
#define NBATCH 65536
#define NB 32   // batch elems per block (R5 geometry: best measured)
// 2*log2(e): folds tanh's 2*v AND exp->exp2 into the f32 weight/bias prescale
// (applied before bf16 rounding: no extra quantization error).
#define WSCALE 2.8853900817779268f

typedef __attribute__((ext_vector_type(4))) float f32x4;
typedef __attribute__((ext_vector_type(8))) short bf16x8;
typedef __attribute__((ext_vector_type(4))) short bf16x4;

#define MFMA(A, B, C) __builtin_amdgcn_mfma_f32_16x16x32_bf16(A, B, C, 0, 0, 0)
// Anti-rematerialization pin (R5-verified: stops weight re-loads in t-loop).
#define PIN(v) asm volatile("" : "+v"(v))

static __device__ __forceinline__ float fexp2(float x) {
#if __has_builtin(__builtin_amdgcn_exp2f)
    return __builtin_amdgcn_exp2f(x);   // v_exp_f32 (2^x)
#else
    return __expf(x * 0.6931471805599453f);
#endif
}
// y = 2*v*log2(e) (prescaled weights): tanh(v) = 1 - 2/(2^y + 1)
static __device__ __forceinline__ float tanh2(float y) {
    float e = fexp2(y);
    return fmaf(-2.0f, __builtin_amdgcn_rcpf(e + 1.0f), 1.0f);
}
static __device__ __forceinline__ short f2bf(float f) {
    __hip_bfloat16 h = __float2bfloat16(f);
    union { __hip_bfloat16 h; short s; } u; u.h = h;
    return u.s;
}
static __device__ __forceinline__ bf16x8 pack8(f32x4 a, f32x4 b) {
    bf16x8 r;
    r[0] = f2bf(a[0]); r[1] = f2bf(a[1]); r[2] = f2bf(a[2]); r[3] = f2bf(a[3]);
    r[4] = f2bf(b[0]); r[5] = f2bf(b[1]); r[6] = f2bf(b[2]); r[7] = f2bf(b[3]);
    return r;
}
static __device__ __forceinline__ bf16x8 loadw8(const float* p) {
    return pack8(*(const f32x4*)p, *(const f32x4*)(p + 4));
}
static __device__ __forceinline__ bf16x8 loadw8s(const float* p, float s) {
    f32x4 a = *(const f32x4*)p, b = *(const f32x4*)(p + 4);
    return pack8(a * s, b * s);
}

// R5 structure (WG = 256 = 4 waves, 32 batch/block, 42 barriers) + R8 VALU
// cuts (WSCALE prescale, exp2 tanh, bias-as-acc-init) + 6 blocks/CU residency.
// A = weights (VGPR bf16, PINned); B = activations (LDS bf16); D = preact f32.
// Frag maps (R3+ HW-verified): A row=c, k=32f+8g+j; B col=c, same k;
// D col=c, row=4g+r. D->B repack: kg=2mt+(g>>1), e=4(g&1)+r.
__global__ __launch_bounds__(256, 6) void rnn_mfma(
    const float* __restrict__ x,     // [B, T, 24]
    const float* __restrict__ h0in,  // [3, B, 64]
    const float* __restrict__ pWi0, const float* __restrict__ pWh0,
    const float* __restrict__ pbi0, const float* __restrict__ pbh0,
    const float* __restrict__ pWi1, const float* __restrict__ pWh1,
    const float* __restrict__ pbi1, const float* __restrict__ pbh1,
    const float* __restrict__ pWi2, const float* __restrict__ pWh2,
    const float* __restrict__ pbi2, const float* __restrict__ pbh2,
    const float* __restrict__ pWout, const float* __restrict__ pbout,
    float* __restrict__ out)         // [B*10] ++ [3*B*64]
{
    __shared__ __align__(16) short hbuf[2][3][8][NB][8];  // 24 KB

    const int tid  = threadIdx.x;
    const int lane = tid & 63;
    const int g    = lane >> 4;      // k-group 0..3
    const int c    = lane & 15;      // col-in-n-tile / A-row-in-tile
    const int mt   = tid >> 6;       // wave id = m-tile 0..3
    const int b0   = blockIdx.x * NB;

    // ---- init hbuf parity 0 from h0 (bf16) ----
    {
        const int b = tid & 31, k8 = (tid >> 5) & 7;
#pragma unroll
        for (int l = 0; l < 3; ++l) {
            const float* p = h0in + ((size_t)l * NBATCH + (b0 + b)) * H + k8 * 8;
            *(bf16x8*)&hbuf[0][l][k8][b][0] =
                pack8(*(const f32x4*)p, *(const f32x4*)(p + 4));
        }
    }

    // ---- weight A-fragments (bf16, prescaled, pinned) ----
    const int ia = mt * 16 + c;
    bf16x8 aWi0;
    if (g < 3) aWi0 = loadw8s(pWi0 + ia * IN + g * 8, WSCALE);
    else {
#pragma unroll
        for (int j = 0; j < 8; ++j) aWi0[j] = 0;   // k = 24..31 zero pad
    }
    PIN(aWi0);
    bf16x8 aWh0[2], aWi1[2], aWh1[2], aWi2[2], aWh2[2];
#pragma unroll
    for (int kt = 0; kt < 2; ++kt) {
        aWh0[kt] = loadw8s(pWh0 + ia * H + kt * 32 + g * 8, WSCALE);  PIN(aWh0[kt]);
        aWi1[kt] = loadw8s(pWi1 + ia * H + kt * 32 + g * 8, WSCALE);  PIN(aWi1[kt]);
        aWh1[kt] = loadw8s(pWh1 + ia * H + kt * 32 + g * 8, WSCALE);  PIN(aWh1[kt]);
        aWi2[kt] = loadw8s(pWi2 + ia * H + kt * 32 + g * 8, WSCALE);  PIN(aWi2[kt]);
        aWh2[kt] = loadw8s(pWh2 + ia * H + kt * 32 + g * 8, WSCALE);  PIN(aWh2[kt]);
    }

    // ---- scaled bias per D-row (acc-init vectors), pinned ----
    const int i0 = mt * 16 + g * 4;
    f32x4 bs0 = (*(const f32x4*)(pbi0 + i0) + *(const f32x4*)(pbh0 + i0)) * WSCALE;
    f32x4 bs1 = (*(const f32x4*)(pbi1 + i0) + *(const f32x4*)(pbh1 + i0)) * WSCALE;
    f32x4 bs2 = (*(const f32x4*)(pbi2 + i0) + *(const f32x4*)(pbh2 + i0)) * WSCALE;
    PIN(bs0); PIN(bs1); PIN(bs2);

    const int kgw = mt * 2 + (g >> 1);   // repack write kg
    const int eb  = (g & 1) * 4;         // repack write elem base

    const float* xb0 = x + (size_t)(b0 + c) * (SEQ * IN) + g * 8;        // nt0
    const float* xb1 = x + (size_t)(b0 + 16 + c) * (SEQ * IN) + g * 8;   // nt1
    float* hsout = out + (size_t)NBATCH * CLS;

    __syncthreads();

#pragma unroll 1
    for (int t = 0; t < SEQ; ++t) {
        const int p = t & 1, q = p ^ 1;
        // ======== L0: below = x (global), self = hbuf[p][0] -> hbuf[q][0]
        {
            bf16x8 bx0, bx1;
#pragma unroll
            for (int j = 0; j < 8; ++j) { bx0[j] = 0; bx1[j] = 0; }
            if (g < 3) {
                const float* p0 = xb0 + t * IN;
                const float* p1 = xb1 + t * IN;
                bx0 = pack8(*(const f32x4*)p0, *(const f32x4*)(p0 + 4));
                bx1 = pack8(*(const f32x4*)p1, *(const f32x4*)(p1 + 4));
            }
            bf16x8 s0a = *(const bf16x8*)&hbuf[p][0][g][c][0];
            bf16x8 s0b = *(const bf16x8*)&hbuf[p][0][g][c + 16][0];
            bf16x8 s1a = *(const bf16x8*)&hbuf[p][0][4 + g][c][0];
            bf16x8 s1b = *(const bf16x8*)&hbuf[p][0][4 + g][c + 16][0];
            f32x4 a0 = bs0, a1 = bs0;            // bias as C-init
            a0 = MFMA(aWh0[0], s0a, a0);  a1 = MFMA(aWh0[0], s0b, a1);
            a0 = MFMA(aWh0[1], s1a, a0);  a1 = MFMA(aWh0[1], s1b, a1);
            a0 = MFMA(aWi0,    bx0, a0);  a1 = MFMA(aWi0,    bx1, a1);
            f32x4 t0, t1;
#pragma unroll
            for (int r = 0; r < 4; ++r) {
                t0[r] = tanh2(a0[r]);
                t1[r] = tanh2(a1[r]);
            }
            if (t == SEQ - 1) {
                *(f32x4*)(hsout + (size_t)(b0 + c) * H + i0) = t0;
                *(f32x4*)(hsout + (size_t)(b0 + 16 + c) * H + i0) = t1;
            }
            bf16x4 p0v, p1v;
#pragma unroll
            for (int r = 0; r < 4; ++r) { p0v[r] = f2bf(t0[r]); p1v[r] = f2bf(t1[r]); }
            *(bf16x4*)&hbuf[q][0][kgw][c][eb] = p0v;
            *(bf16x4*)&hbuf[q][0][kgw][c + 16][eb] = p1v;
            __syncthreads();   // new h0 visible
        }
        // ======== L1 / L2 ========
#define LAYER12(li, bsv, aWhX, aWiX)                                            \
        {                                                                       \
            bf16x8 s0a = *(const bf16x8*)&hbuf[p][li][g][c][0];                 \
            bf16x8 s0b = *(const bf16x8*)&hbuf[p][li][g][c + 16][0];            \
            bf16x8 s1a = *(const bf16x8*)&hbuf[p][li][4 + g][c][0];             \
            bf16x8 s1b = *(const bf16x8*)&hbuf[p][li][4 + g][c + 16][0];        \
            bf16x8 b0a = *(const bf16x8*)&hbuf[q][li - 1][g][c][0];             \
            bf16x8 b0b = *(const bf16x8*)&hbuf[q][li - 1][g][c + 16][0];        \
            bf16x8 b1a = *(const bf16x8*)&hbuf[q][li - 1][4 + g][c][0];         \
            bf16x8 b1b = *(const bf16x8*)&hbuf[q][li - 1][4 + g][c + 16][0];    \
            f32x4 a0 = bsv, a1 = bsv;                                           \
            a0 = MFMA(aWhX[0], s0a, a0);  a1 = MFMA(aWhX[0], s0b, a1);          \
            a0 = MFMA(aWhX[1], s1a, a0);  a1 = MFMA(aWhX[1], s1b, a1);          \
            a0 = MFMA(aWiX[0], b0a, a0);  a1 = MFMA(aWiX[0], b0b, a1);          \
            a0 = MFMA(aWiX[1], b1a, a0);  a1 = MFMA(aWiX[1], b1b, a1);          \
            f32x4 t0, t1;                                                       \
            _Pragma("unroll")                                                   \
            for (int r = 0; r < 4; ++r) {                                       \
                t0[r] = tanh2(a0[r]);                                           \
                t1[r] = tanh2(a1[r]);                                           \
            }                                                                   \
            if (t == SEQ - 1) {                                                 \
                float* hp = hsout + (size_t)(li) * NBATCH * H;                  \
                *(f32x4*)(hp + (size_t)(b0 + c) * H + i0) = t0;                 \
                *(f32x4*)(hp + (size_t)(b0 + 16 + c) * H + i0) = t1;            \
            }                                                                   \
            bf16x4 p0v, p1v;                                                    \
            _Pragma("unroll")                                                   \
            for (int r = 0; r < 4; ++r) { p0v[r] = f2bf(t0[r]);                 \
                                          p1v[r] = f2bf(t1[r]); }               \
            *(bf16x4*)&hbuf[q][li][kgw][c][eb] = p0v;                           \
            *(bf16x4*)&hbuf[q][li][kgw][c + 16][eb] = p1v;                      \
            __syncthreads();                                                    \
        }
        LAYER12(1, bs1, aWh1, aWi1)
        LAYER12(2, bs2, aWh2, aWi2)
#undef LAYER12
    }

    // ===== logits head (MFMA, waves 0-1). Final h2 in parity 0 (SEQ even).
    if (mt < 2) {
        bf16x8 aWo0, aWo1;
#pragma unroll
        for (int j = 0; j < 8; ++j) { aWo0[j] = 0; aWo1[j] = 0; }
        if (c < CLS) {
            aWo0 = loadw8(pWout + c * H + 8 * g);         // unscaled: no tanh
            aWo1 = loadw8(pWout + c * H + 32 + 8 * g);
        }
        const int col = c + 16 * mt;
        bf16x8 s0 = *(const bf16x8*)&hbuf[0][2][g][col][0];
        bf16x8 s1 = *(const bf16x8*)&hbuf[0][2][4 + g][col][0];
        f32x4 acc = {0.f, 0.f, 0.f, 0.f};
        acc = MFMA(aWo0, s0, acc);
        acc = MFMA(aWo1, s1, acc);
#pragma unroll
        for (int r = 0; r < 4; ++r) {
            const int cls = 4 * g + r;
            if (cls < CLS)
                out[(size_t)(b0 + col) * CLS + cls] = acc[r] + pbout[cls];
        }
    }
}

extern "C" void kernel_launch(void* const* d_in, const int* in_sizes, int n_in,
                              void* d_out, int out_size, void* d_ws, size_t ws_size,
                              hipStream_t stream) {
    const float* x    = (const float*)d_in[0];
    const float* h0in = (const float*)d_in[1];
    const float* Wi0  = (const float*)d_in[2];
    const float* Wh0  = (const float*)d_in[3];
    const float* bi0  = (const float*)d_in[4];
    const float* bh0  = (const float*)d_in[5];
    const float* Wi1  = (const float*)d_in[6];
    const float* Wh1  = (const float*)d_in[7];
    const float* bi1  = (const float*)d_in[8];
    const float* bh1  = (const float*)d_in[9];
    const float* Wi2  = (const float*)d_in[10];
    const float* Wh2  = (const float*)d_in[11];
    const float* bi2  = (const float*)d_in[12];
    const float* bh2  = (const float*)d_in[13];
    const float* Wout = (const float*)d_in[14];
    const float* bout = (const float*)d_in[15];
    float* out = (float*)d_out;

    dim3 grid(NBATCH / NB), block(256);
    rnn_mfma<<<grid, block, 0, stream>>>(x, h0in, Wi0, Wh0, bi0, bh0,
                                         Wi1, Wh1, bi1, bh1,
                                         Wi2, Wh2, bi2, bh2,
                                         Wout, bout, out);
}

// Round 10
// 116.526 us; speedup vs baseline: 1.1969x; 1.1969x over previous
//
#include <hip/hip_runtime.h>
#include <hip/hip_bf16.h>

#define SEQ 14
#define IN 24
#define H 64
#define CLS 10
#define NBATCH 65536
#define NB 32   // batch elems per block
// 2*log2(e): folds tanh's 2*v AND exp->exp2 into the f32 weight/bias prescale.
#define WSCALE 2.8853900817779268f

typedef __attribute__((ext_vector_type(4))) float f32x4;
typedef __attribute__((ext_vector_type(8))) short bf16x8;
typedef __attribute__((ext_vector_type(4))) short bf16x4;

#define MFMA(A, B, C) __builtin_amdgcn_mfma_f32_16x16x32_bf16(A, B, C, 0, 0, 0)
// Anti-rematerialization pin (R5-verified).
#define PIN(v) asm volatile("" : "+v"(v))

static __device__ __forceinline__ float fexp2(float x) {
#if __has_builtin(__builtin_amdgcn_exp2f)
    return __builtin_amdgcn_exp2f(x);   // v_exp_f32 (2^x)
#else
    return __expf(x * 0.6931471805599453f);
#endif
}
// y = 2*v*log2(e) (prescaled weights): tanh(v) = 1 - 2/(2^y + 1)
static __device__ __forceinline__ float tanh2(float y) {
    float e = fexp2(y);
    return fmaf(-2.0f, __builtin_amdgcn_rcpf(e + 1.0f), 1.0f);
}
static __device__ __forceinline__ short f2bf(float f) {
    __hip_bfloat16 h = __float2bfloat16(f);
    union { __hip_bfloat16 h; short s; } u; u.h = h;
    return u.s;
}
static __device__ __forceinline__ bf16x8 pack8(f32x4 a, f32x4 b) {
    bf16x8 r;
    r[0] = f2bf(a[0]); r[1] = f2bf(a[1]); r[2] = f2bf(a[2]); r[3] = f2bf(a[3]);
    r[4] = f2bf(b[0]); r[5] = f2bf(b[1]); r[6] = f2bf(b[2]); r[7] = f2bf(b[3]);
    return r;
}
static __device__ __forceinline__ bf16x8 loadw8(const float* p) {
    return pack8(*(const f32x4*)p, *(const f32x4*)(p + 4));
}
static __device__ __forceinline__ bf16x8 loadw8s(const float* p, float s) {
    f32x4 a = *(const f32x4*)p, b = *(const f32x4*)(p + 4);
    return pack8(a * s, b * s);
}

// W=2 variant: block = 128 thr = 2 waves, 32 batch elems. Each wave owns
// 2 m-tiles (32 of 64 i-rows) for ALL layers -> LDS read duplication 4x -> 2x
// (each operand tile is read by 2 waves instead of 4). 42 barriers unchanged,
// but each barrier syncs only 2 waves. Weights: 88 VGPR pinned + 24 bias.
// Frag maps (R3+ HW-verified): A row=c, k=32f+8g+j; B col=c, same k;
// D col=c, row=4g+r. D->B repack: kg=2*MT+(g>>1), e=4(g&1)+r (MT = global
// m-tile = 2*wid + mtl).
__global__ __launch_bounds__(128, 3) void rnn_mfma(
    const float* __restrict__ x,     // [B, T, 24]
    const float* __restrict__ h0in,  // [3, B, 64]
    const float* __restrict__ pWi0, const float* __restrict__ pWh0,
    const float* __restrict__ pbi0, const float* __restrict__ pbh0,
    const float* __restrict__ pWi1, const float* __restrict__ pWh1,
    const float* __restrict__ pbi1, const float* __restrict__ pbh1,
    const float* __restrict__ pWi2, const float* __restrict__ pWh2,
    const float* __restrict__ pbi2, const float* __restrict__ pbh2,
    const float* __restrict__ pWout, const float* __restrict__ pbout,
    float* __restrict__ out)         // [B*10] ++ [3*B*64]
{
    __shared__ __align__(16) short hbuf[2][3][8][NB][8];  // 24 KB

    const int tid  = threadIdx.x;
    const int lane = tid & 63;
    const int g    = lane >> 4;      // k-group 0..3
    const int c    = lane & 15;      // col-in-n-tile / A-row-in-tile
    const int wid  = tid >> 6;       // wave id 0..1 (rows wid*32 .. wid*32+31)
    const int b0   = blockIdx.x * NB;

    // ---- init hbuf parity 0 from h0 (bf16): 768 vec8 slots, 6 per thread ----
    for (int sl = tid; sl < 768; sl += 128) {
        const int ll = sl >> 8, rem = sl & 255, kg = rem >> 5, col = rem & 31;
        const float* pp = h0in + ((size_t)ll * NBATCH + b0 + col) * H + kg * 8;
        *(bf16x8*)&hbuf[0][ll][kg][col][0] =
            pack8(*(const f32x4*)pp, *(const f32x4*)(pp + 4));
    }

    // ---- weight A-fragments (bf16, prescaled, pinned): 88 VGPR ----
    bf16x8 aWh0[2][2], aWh1[2][2], aWh2[2][2], aWi1[2][2], aWi2[2][2], aWi0[2];
#pragma unroll
    for (int mtl = 0; mtl < 2; ++mtl) {
        const int row = wid * 32 + mtl * 16 + c;
#pragma unroll
        for (int f = 0; f < 2; ++f) {
            aWh0[mtl][f] = loadw8s(pWh0 + row * H + 32 * f + 8 * g, WSCALE); PIN(aWh0[mtl][f]);
            aWi1[mtl][f] = loadw8s(pWi1 + row * H + 32 * f + 8 * g, WSCALE); PIN(aWi1[mtl][f]);
            aWh1[mtl][f] = loadw8s(pWh1 + row * H + 32 * f + 8 * g, WSCALE); PIN(aWh1[mtl][f]);
            aWi2[mtl][f] = loadw8s(pWi2 + row * H + 32 * f + 8 * g, WSCALE); PIN(aWi2[mtl][f]);
            aWh2[mtl][f] = loadw8s(pWh2 + row * H + 32 * f + 8 * g, WSCALE); PIN(aWh2[mtl][f]);
        }
        if (g < 3) aWi0[mtl] = loadw8s(pWi0 + row * IN + 8 * g, WSCALE);
        else {
#pragma unroll
            for (int j = 0; j < 8; ++j) aWi0[mtl][j] = 0;   // k=24..31 zero pad
        }
        PIN(aWi0[mtl]);
    }

    // ---- scaled bias acc-init vectors (24 VGPR, pinned) ----
    f32x4 bs0[2], bs1[2], bs2[2];
#pragma unroll
    for (int mtl = 0; mtl < 2; ++mtl) {
        const int i0 = wid * 32 + mtl * 16 + 4 * g;
        bs0[mtl] = (*(const f32x4*)(pbi0 + i0) + *(const f32x4*)(pbh0 + i0)) * WSCALE;
        bs1[mtl] = (*(const f32x4*)(pbi1 + i0) + *(const f32x4*)(pbh1 + i0)) * WSCALE;
        bs2[mtl] = (*(const f32x4*)(pbi2 + i0) + *(const f32x4*)(pbh2 + i0)) * WSCALE;
        PIN(bs0[mtl]); PIN(bs1[mtl]); PIN(bs2[mtl]);
    }

    const int eb = (g & 1) * 4;          // repack write elem base
    float* hsout = out + (size_t)NBATCH * CLS;

    __syncthreads();

#pragma unroll 1
    for (int t = 0; t < SEQ; ++t) {
        const int p = t & 1, q = p ^ 1;
        // ======== L0: below = x (global), self = hbuf[p][0] -> hbuf[q][0]
        {
#pragma unroll
            for (int ch = 0; ch < 2; ++ch) {
                const int col = c + 16 * ch;
                bf16x8 xB;
#pragma unroll
                for (int j = 0; j < 8; ++j) xB[j] = 0;
                if (g < 3) {
                    const float* xp = x + ((size_t)(b0 + col) * SEQ + t) * IN + 8 * g;
                    xB = pack8(*(const f32x4*)xp, *(const f32x4*)(xp + 4));
                }
                bf16x8 s0 = *(const bf16x8*)&hbuf[p][0][g][col][0];
                bf16x8 s1 = *(const bf16x8*)&hbuf[p][0][4 + g][col][0];
#pragma unroll
                for (int mtl = 0; mtl < 2; ++mtl) {
                    f32x4 acc = bs0[mtl];            // bias as C-init
                    acc = MFMA(aWh0[mtl][0], s0, acc);
                    acc = MFMA(aWh0[mtl][1], s1, acc);
                    acc = MFMA(aWi0[mtl], xB, acc);
                    f32x4 th;
#pragma unroll
                    for (int r = 0; r < 4; ++r) th[r] = tanh2(acc[r]);
                    if (t == SEQ - 1)
                        *(f32x4*)(hsout + (size_t)(b0 + col) * H +
                                  wid * 32 + mtl * 16 + 4 * g) = th;
                    bf16x4 pv;
#pragma unroll
                    for (int r = 0; r < 4; ++r) pv[r] = f2bf(th[r]);
                    *(bf16x4*)&hbuf[q][0][4 * wid + 2 * mtl + (g >> 1)][col][eb] = pv;
                }
            }
            __syncthreads();   // new h0 visible to both waves
        }
        // ======== L1 / L2 ========
#define LAYER12(li, bsv, aWhX, aWiX)                                            \
        {                                                                       \
            _Pragma("unroll")                                                   \
            for (int ch = 0; ch < 2; ++ch) {                                    \
                const int col = c + 16 * ch;                                    \
                bf16x8 s0 = *(const bf16x8*)&hbuf[p][li][g][col][0];            \
                bf16x8 s1 = *(const bf16x8*)&hbuf[p][li][4 + g][col][0];        \
                bf16x8 u0 = *(const bf16x8*)&hbuf[q][li - 1][g][col][0];        \
                bf16x8 u1 = *(const bf16x8*)&hbuf[q][li - 1][4 + g][col][0];    \
                _Pragma("unroll")                                               \
                for (int mtl = 0; mtl < 2; ++mtl) {                             \
                    f32x4 acc = bsv[mtl];                                       \
                    acc = MFMA(aWhX[mtl][0], s0, acc);                          \
                    acc = MFMA(aWhX[mtl][1], s1, acc);                          \
                    acc = MFMA(aWiX[mtl][0], u0, acc);                          \
                    acc = MFMA(aWiX[mtl][1], u1, acc);                          \
                    f32x4 th;                                                   \
                    _Pragma("unroll")                                           \
                    for (int r = 0; r < 4; ++r) th[r] = tanh2(acc[r]);          \
                    if (t == SEQ - 1)                                           \
                        *(f32x4*)(hsout + (size_t)(li) * NBATCH * H +           \
                                  (size_t)(b0 + col) * H +                      \
                                  wid * 32 + mtl * 16 + 4 * g) = th;            \
                    bf16x4 pv;                                                  \
                    _Pragma("unroll")                                           \
                    for (int r = 0; r < 4; ++r) pv[r] = f2bf(th[r]);            \
                    *(bf16x4*)&hbuf[q][li][4 * wid + 2 * mtl + (g >> 1)]        \
                        [col][eb] = pv;                                         \
                }                                                               \
            }                                                                   \
            __syncthreads();                                                    \
        }
        LAYER12(1, bs1, aWh1, aWi1)
        LAYER12(2, bs2, aWh2, aWi2)
#undef LAYER12
    }

    // ===== logits head (MFMA, both waves). Final h2 in parity 0 (SEQ even).
    {
        bf16x8 aWo0, aWo1;
#pragma unroll
        for (int j = 0; j < 8; ++j) { aWo0[j] = 0; aWo1[j] = 0; }
        if (c < CLS) {
            aWo0 = loadw8(pWout + c * H + 8 * g);         // unscaled: no tanh
            aWo1 = loadw8(pWout + c * H + 32 + 8 * g);
        }
        const int col = c + 16 * wid;
        bf16x8 s0 = *(const bf16x8*)&hbuf[0][2][g][col][0];
        bf16x8 s1 = *(const bf16x8*)&hbuf[0][2][4 + g][col][0];
        f32x4 acc = {0.f, 0.f, 0.f, 0.f};
        acc = MFMA(aWo0, s0, acc);
        acc = MFMA(aWo1, s1, acc);
#pragma unroll
        for (int r = 0; r < 4; ++r) {
            const int cls = 4 * g + r;
            if (cls < CLS)
                out[(size_t)(b0 + col) * CLS + cls] = acc[r] + pbout[cls];
        }
    }
}

extern "C" void kernel_launch(void* const* d_in, const int* in_sizes, int n_in,
                              void* d_out, int out_size, void* d_ws, size_t ws_size,
                              hipStream_t stream) {
    const float* x    = (const float*)d_in[0];
    const float* h0in = (const float*)d_in[1];
    const float* Wi0  = (const float*)d_in[2];
    const float* Wh0  = (const float*)d_in[3];
    const float* bi0  = (const float*)d_in[4];
    const float* bh0  = (const float*)d_in[5];
    const float* Wi1  = (const float*)d_in[6];
    const float* Wh1  = (const float*)d_in[7];
    const float* bi1  = (const float*)d_in[8];
    const float* bh1  = (const float*)d_in[9];
    const float* Wi2  = (const float*)d_in[10];
    const float* Wh2  = (const float*)d_in[11];
    const float* bi2  = (const float*)d_in[12];
    const float* bh2  = (const float*)d_in[13];
    const float* Wout = (const float*)d_in[14];
    const float* bout = (const float*)d_in[15];
    float* out = (float*)d_out;

    dim3 grid(NBATCH / NB), block(128);
    rnn_mfma<<<grid, block, 0, stream>>>(x, h0in, Wi0, Wh0, bi0, bh0,
                                         Wi1, Wh1, bi1, bh1,
                                         Wi2, Wh2, bi2, bh2,
                                         Wout, bout, out);
}

// Round 11
// 92.103 us; speedup vs baseline: 1.5142x; 1.2652x over previous
//
#include <hip/hip_runtime.h>
#include <hip/hip_bf16.h>

#define SEQ 14
#define IN 24
#define H 64
#define CLS 10
#define NBATCH 65536
#define NB 32   // batch elems per block (R5 geometry: best measured)
// 2*log2(e): folds tanh's 2*v AND exp->exp2 into the f32 weight/bias prescale.
#define WSCALE 2.8853900817779268f

typedef __attribute__((ext_vector_type(4))) float f32x4;
typedef __attribute__((ext_vector_type(8))) short bf16x8;
typedef __attribute__((ext_vector_type(4))) short bf16x4;

#define MFMA(A, B, C) __builtin_amdgcn_mfma_f32_16x16x32_bf16(A, B, C, 0, 0, 0)
// Anti-rematerialization pin (R5-verified).
#define PIN(v) asm volatile("" : "+v"(v))

static __device__ __forceinline__ float fexp2(float x) {
#if __has_builtin(__builtin_amdgcn_exp2f)
    return __builtin_amdgcn_exp2f(x);   // v_exp_f32 (2^x)
#else
    return __expf(x * 0.6931471805599453f);
#endif
}
// y = 2*v*log2(e) (prescaled weights): tanh(v) = 1 - 2/(2^y + 1)
static __device__ __forceinline__ float tanh2(float y) {
    float e = fexp2(y);
    return fmaf(-2.0f, __builtin_amdgcn_rcpf(e + 1.0f), 1.0f);
}
static __device__ __forceinline__ short f2bf(float f) {
    __hip_bfloat16 h = __float2bfloat16(f);
    union { __hip_bfloat16 h; short s; } u; u.h = h;
    return u.s;
}
static __device__ __forceinline__ bf16x8 pack8(f32x4 a, f32x4 b) {
    bf16x8 r;
    r[0] = f2bf(a[0]); r[1] = f2bf(a[1]); r[2] = f2bf(a[2]); r[3] = f2bf(a[3]);
    r[4] = f2bf(b[0]); r[5] = f2bf(b[1]); r[6] = f2bf(b[2]); r[7] = f2bf(b[3]);
    return r;
}
static __device__ __forceinline__ bf16x8 loadw8(const float* p) {
    return pack8(*(const f32x4*)p, *(const f32x4*)(p + 4));
}
static __device__ __forceinline__ bf16x8 loadw8s(const float* p, float s) {
    f32x4 a = *(const f32x4*)p, b = *(const f32x4*)(p + 4);
    return pack8(a * s, b * s);
}

// R5 structure + SKEWED intervals: interval s computes {L0(t=s), L1(t=s-1),
// L2(t=s-2)} -- mutually independent -> straight-line body with 6 independent
// chains (3 layers x 2 n-tiles), ONE barrier per interval, 16 intervals
// (vs R5's 42). Reads at s hit parity (s-1)&1; writes parity s&1; one barrier
// orders RAW+WAR. h_l(init) preloaded to parity (l+1)&1 (R7-verified).
// Frag maps (R3+ HW-verified): A row=c, k=32f+8g+j; B col=c, same k;
// D col=c, row=4g+r. D->B repack: kg=2mt+(g>>1), e=4(g&1)+r.
__global__ __launch_bounds__(256, 2) void rnn_mfma(
    const float* __restrict__ x,     // [B, T, 24]
    const float* __restrict__ h0in,  // [3, B, 64]
    const float* __restrict__ pWi0, const float* __restrict__ pWh0,
    const float* __restrict__ pbi0, const float* __restrict__ pbh0,
    const float* __restrict__ pWi1, const float* __restrict__ pWh1,
    const float* __restrict__ pbi1, const float* __restrict__ pbh1,
    const float* __restrict__ pWi2, const float* __restrict__ pWh2,
    const float* __restrict__ pbi2, const float* __restrict__ pbh2,
    const float* __restrict__ pWout, const float* __restrict__ pbout,
    float* __restrict__ out)         // [B*10] ++ [3*B*64]
{
    __shared__ __align__(16) short hbuf[2][3][8][NB][8];  // 24 KB

    const int tid  = threadIdx.x;
    const int lane = tid & 63;
    const int g    = lane >> 4;      // k-group 0..3
    const int c    = lane & 15;      // col-in-n-tile / A-row-in-tile
    const int mt   = tid >> 6;       // wave id = m-tile 0..3
    const int b0   = blockIdx.x * NB;

    // ---- preload h_l(init) -> hbuf[(l+1)&1][l] (bf16) ----
    {
        const int b = tid & 31, k8 = (tid >> 5) & 7;
#pragma unroll
        for (int l = 0; l < 3; ++l) {
            const float* p = h0in + ((size_t)l * NBATCH + (b0 + b)) * H + k8 * 8;
            *(bf16x8*)&hbuf[(l + 1) & 1][l][k8][b][0] =
                pack8(*(const f32x4*)p, *(const f32x4*)(p + 4));
        }
    }

    // ---- weight A-fragments (bf16, prescaled, pinned) ----
    const int ia = mt * 16 + c;
    bf16x8 aWi0;
    if (g < 3) aWi0 = loadw8s(pWi0 + ia * IN + g * 8, WSCALE);
    else {
#pragma unroll
        for (int j = 0; j < 8; ++j) aWi0[j] = 0;   // k = 24..31 zero pad
    }
    PIN(aWi0);
    bf16x8 aWh0[2], aWi1[2], aWh1[2], aWi2[2], aWh2[2];
#pragma unroll
    for (int kt = 0; kt < 2; ++kt) {
        aWh0[kt] = loadw8s(pWh0 + ia * H + kt * 32 + g * 8, WSCALE);  PIN(aWh0[kt]);
        aWi1[kt] = loadw8s(pWi1 + ia * H + kt * 32 + g * 8, WSCALE);  PIN(aWi1[kt]);
        aWh1[kt] = loadw8s(pWh1 + ia * H + kt * 32 + g * 8, WSCALE);  PIN(aWh1[kt]);
        aWi2[kt] = loadw8s(pWi2 + ia * H + kt * 32 + g * 8, WSCALE);  PIN(aWi2[kt]);
        aWh2[kt] = loadw8s(pWh2 + ia * H + kt * 32 + g * 8, WSCALE);  PIN(aWh2[kt]);
    }

    // ---- scaled bias acc-init vectors, pinned ----
    const int i0 = mt * 16 + g * 4;
    f32x4 bs0 = (*(const f32x4*)(pbi0 + i0) + *(const f32x4*)(pbh0 + i0)) * WSCALE;
    f32x4 bs1 = (*(const f32x4*)(pbi1 + i0) + *(const f32x4*)(pbh1 + i0)) * WSCALE;
    f32x4 bs2 = (*(const f32x4*)(pbi2 + i0) + *(const f32x4*)(pbh2 + i0)) * WSCALE;
    PIN(bs0); PIN(bs1); PIN(bs2);

    const int kgw = mt * 2 + (g >> 1);   // repack write kg
    const int eb  = (g & 1) * 4;         // repack write elem base

    const float* xb0 = x + (size_t)(b0 + c) * (SEQ * IN) + g * 8;        // nt0
    const float* xb1 = x + (size_t)(b0 + 16 + c) * (SEQ * IN) + g * 8;   // nt1
    float* hsout = out + (size_t)NBATCH * CLS;

    __syncthreads();

// ---- layer-step macros; s_ determines parities: read (s_-1)&1 == (s_+1)&1,
// ---- write s_&1. All verified index maps from R5.
#define L0S(s_)                                                                 \
    {                                                                           \
        const int pr = ((s_) + 1) & 1, pw = (s_) & 1, t = (s_);                 \
        bf16x8 bx0, bx1;                                                        \
        _Pragma("unroll")                                                       \
        for (int j = 0; j < 8; ++j) { bx0[j] = 0; bx1[j] = 0; }                 \
        if (g < 3) {                                                            \
            const float* p0 = xb0 + t * IN;                                     \
            const float* p1 = xb1 + t * IN;                                     \
            bx0 = pack8(*(const f32x4*)p0, *(const f32x4*)(p0 + 4));            \
            bx1 = pack8(*(const f32x4*)p1, *(const f32x4*)(p1 + 4));            \
        }                                                                       \
        bf16x8 s0a = *(const bf16x8*)&hbuf[pr][0][g][c][0];                     \
        bf16x8 s0b = *(const bf16x8*)&hbuf[pr][0][g][c + 16][0];                \
        bf16x8 s1a = *(const bf16x8*)&hbuf[pr][0][4 + g][c][0];                 \
        bf16x8 s1b = *(const bf16x8*)&hbuf[pr][0][4 + g][c + 16][0];            \
        f32x4 a0 = bs0, a1 = bs0;                                               \
        a0 = MFMA(aWh0[0], s0a, a0);  a1 = MFMA(aWh0[0], s0b, a1);              \
        a0 = MFMA(aWh0[1], s1a, a0);  a1 = MFMA(aWh0[1], s1b, a1);              \
        a0 = MFMA(aWi0,    bx0, a0);  a1 = MFMA(aWi0,    bx1, a1);              \
        f32x4 t0, t1;                                                           \
        _Pragma("unroll")                                                       \
        for (int r = 0; r < 4; ++r) { t0[r] = tanh2(a0[r]); t1[r] = tanh2(a1[r]); } \
        if (t == SEQ - 1) {                                                     \
            *(f32x4*)(hsout + (size_t)(b0 + c) * H + i0) = t0;                  \
            *(f32x4*)(hsout + (size_t)(b0 + 16 + c) * H + i0) = t1;             \
        }                                                                       \
        bf16x4 p0v, p1v;                                                        \
        _Pragma("unroll")                                                       \
        for (int r = 0; r < 4; ++r) { p0v[r] = f2bf(t0[r]); p1v[r] = f2bf(t1[r]); } \
        *(bf16x4*)&hbuf[pw][0][kgw][c][eb] = p0v;                               \
        *(bf16x4*)&hbuf[pw][0][kgw][c + 16][eb] = p1v;                          \
    }

#define L12S(s_, li, bsv, aWhX, aWiX)                                           \
    {                                                                           \
        const int pr = ((s_) + 1) & 1, pw = (s_) & 1, t = (s_) - (li);          \
        bf16x8 s0a = *(const bf16x8*)&hbuf[pr][li][g][c][0];                    \
        bf16x8 s0b = *(const bf16x8*)&hbuf[pr][li][g][c + 16][0];               \
        bf16x8 s1a = *(const bf16x8*)&hbuf[pr][li][4 + g][c][0];                \
        bf16x8 s1b = *(const bf16x8*)&hbuf[pr][li][4 + g][c + 16][0];           \
        bf16x8 b0a = *(const bf16x8*)&hbuf[pr][li - 1][g][c][0];                \
        bf16x8 b0b = *(const bf16x8*)&hbuf[pr][li - 1][g][c + 16][0];           \
        bf16x8 b1a = *(const bf16x8*)&hbuf[pr][li - 1][4 + g][c][0];            \
        bf16x8 b1b = *(const bf16x8*)&hbuf[pr][li - 1][4 + g][c + 16][0];       \
        f32x4 a0 = bsv, a1 = bsv;                                               \
        a0 = MFMA(aWhX[0], s0a, a0);  a1 = MFMA(aWhX[0], s0b, a1);              \
        a0 = MFMA(aWhX[1], s1a, a0);  a1 = MFMA(aWhX[1], s1b, a1);              \
        a0 = MFMA(aWiX[0], b0a, a0);  a1 = MFMA(aWiX[0], b0b, a1);              \
        a0 = MFMA(aWiX[1], b1a, a0);  a1 = MFMA(aWiX[1], b1b, a1);              \
        f32x4 t0, t1;                                                           \
        _Pragma("unroll")                                                       \
        for (int r = 0; r < 4; ++r) { t0[r] = tanh2(a0[r]); t1[r] = tanh2(a1[r]); } \
        if (t == SEQ - 1) {                                                     \
            float* hp = hsout + (size_t)(li) * NBATCH * H;                      \
            *(f32x4*)(hp + (size_t)(b0 + c) * H + i0) = t0;                     \
            *(f32x4*)(hp + (size_t)(b0 + 16 + c) * H + i0) = t1;                \
        }                                                                       \
        bf16x4 p0v, p1v;                                                        \
        _Pragma("unroll")                                                       \
        for (int r = 0; r < 4; ++r) { p0v[r] = f2bf(t0[r]); p1v[r] = f2bf(t1[r]); } \
        *(bf16x4*)&hbuf[pw][li][kgw][c][eb] = p0v;                              \
        *(bf16x4*)&hbuf[pw][li][kgw][c + 16][eb] = p1v;                         \
    }

    // ---- prologue: s=0, s=1 ----
    L0S(0);
    __syncthreads();
    L0S(1);
    L12S(1, 1, bs1, aWh1, aWi1);
    __syncthreads();

    // ---- main loop: s=2..SEQ-1 (straight-line 3-layer body, 1 barrier) ----
#pragma unroll 1
    for (int s = 2; s < SEQ; ++s) {
        L0S(s);
        L12S(s, 1, bs1, aWh1, aWi1);
        L12S(s, 2, bs2, aWh2, aWi2);
        __syncthreads();
    }

    // ---- epilogue: s=SEQ (14), s=SEQ+1 (15) ----
    L12S(SEQ, 1, bs1, aWh1, aWi1);
    L12S(SEQ, 2, bs2, aWh2, aWi2);
    __syncthreads();
    L12S(SEQ + 1, 2, bs2, aWh2, aWi2);
    __syncthreads();

#undef L0S
#undef L12S

    // ===== logits head (MFMA, waves 0-1). Final h2 in parity (SEQ+1)&1 = 1.
    if (mt < 2) {
        bf16x8 aWo0, aWo1;
#pragma unroll
        for (int j = 0; j < 8; ++j) { aWo0[j] = 0; aWo1[j] = 0; }
        if (c < CLS) {
            aWo0 = loadw8(pWout + c * H + 8 * g);         // unscaled: no tanh
            aWo1 = loadw8(pWout + c * H + 32 + 8 * g);
        }
        const int col = c + 16 * mt;
        bf16x8 s0 = *(const bf16x8*)&hbuf[1][2][g][col][0];
        bf16x8 s1 = *(const bf16x8*)&hbuf[1][2][4 + g][col][0];
        f32x4 acc = {0.f, 0.f, 0.f, 0.f};
        acc = MFMA(aWo0, s0, acc);
        acc = MFMA(aWo1, s1, acc);
#pragma unroll
        for (int r = 0; r < 4; ++r) {
            const int cls = 4 * g + r;
            if (cls < CLS)
                out[(size_t)(b0 + col) * CLS + cls] = acc[r] + pbout[cls];
        }
    }
}

extern "C" void kernel_launch(void* const* d_in, const int* in_sizes, int n_in,
                              void* d_out, int out_size, void* d_ws, size_t ws_size,
                              hipStream_t stream) {
    const float* x    = (const float*)d_in[0];
    const float* h0in = (const float*)d_in[1];
    const float* Wi0  = (const float*)d_in[2];
    const float* Wh0  = (const float*)d_in[3];
    const float* bi0  = (const float*)d_in[4];
    const float* bh0  = (const float*)d_in[5];
    const float* Wi1  = (const float*)d_in[6];
    const float* Wh1  = (const float*)d_in[7];
    const float* bi1  = (const float*)d_in[8];
    const float* bh1  = (const float*)d_in[9];
    const float* Wi2  = (const float*)d_in[10];
    const float* Wh2  = (const float*)d_in[11];
    const float* bi2  = (const float*)d_in[12];
    const float* bh2  = (const float*)d_in[13];
    const float* Wout = (const float*)d_in[14];
    const float* bout = (const float*)d_in[15];
    float* out = (float*)d_out;

    dim3 grid(NBATCH / NB), block(256);
    rnn_mfma<<<grid, block, 0, stream>>>(x, h0in, Wi0, Wh0, bi0, bh0,
                                         Wi1, Wh1, bi1, bh1,
                                         Wi2, Wh2, bi2, bh2,
                                         Wout, bout, out);
}